// Round 11
// baseline (59.469 us; speedup 1.0000x reference)
//
#include <hip/hip_runtime.h>
#include <hip/hip_bf16.h>

// ChamferDistanceLoss via exact-integer f16 MFMA (32x32x16).
// MFMA via inline asm with "=&v" EARLY-CLOBBER dests: forces VGPR-class
// accumulators (builtin dests go to AGPRs by allocator policy -> 16
// v_accvgpr_read per consume was the ~34us plateau, R4/R5/R10). NO
// sched_barriers (R9 lesson: order-pinning serializes, m141): ordering is by
// dataflow; the 4x s_nop 7 inside the asm block covers the MFMA->VALU
// dest-read hazard for any post-block schedule.
//   A (rows, L2-streamed)   = refs    enc [rd, rh, rw, nr>>3, nr&7, 0,0,0]
//   B (cols, register-held) = queries enc [-2qd, -2qh, -2qw, 8, 1, 0,0,0]
// B zeroed on lanes>=32 (k=8..15) -> A garbage there nullified.
// s = nr - 2 q.r exact; min commutes with +nq; scale by (2/63)^2 at the end.

#define NVOX      262144
#define NCHUNK    256
#define MAXPTS    10000
#define PTS_PAD   10240
#define NCLOUD    8
#define NTASK     8
#define NRB       40         // reduce blocks per task
#define QPW       64         // queries per wave (2 B-frags x 32)
#define QPB       256        // queries per block (4 waves)
#define NQB       40         // query blocks per task
#define RSPLIT    4          // ref splits per task
#define RLEN      2560       // refs per split
#define RSTEPS    80         // 32-ref steps per split
#define SCALE     (2.0f/63.0f)

typedef _Float16 half8  __attribute__((ext_vector_type(8)));
typedef float    f32x16 __attribute__((ext_vector_type(16)));

// ---------------- workspace layout (bytes) ----------------
#define WS_TOTALS   0           // 8 ints
#define WS_COUNTS   1024        // 8*256 ints
#define WS_OFFSETS  16384       // 8*256 ints
#define WS_QFRAG    32768       // 8*10240*16B = 1310720
#define WS_RFRAG    1343488     // 8*10240*16B = 1310720
#define WS_NQ       2654208     // 8*10240 f32 = 327680
#define WS_SMIN     2981888     // 8*4*10240 f32 = 1310720
#define WS_BSUM     4292608     // 8*40 f32

__device__ __forceinline__ const float* cloud_src(const float* pred, const float* tgt, int cloud) {
    const float* base = (cloud & 1) ? tgt : pred;
    return base + (size_t)(cloud >> 1) * NVOX;
}

// ---- Kernel 1: per-chunk active counts (+ pad init, merged) ----------------
__global__ void k_count(const float* __restrict__ pred, const float* __restrict__ tgt,
                        int* __restrict__ counts,
                        half8* __restrict__ Qfrag, half8* __restrict__ Rfrag,
                        float* __restrict__ nqint) {
    int gi = blockIdx.x * 256 + threadIdx.x;
    if (gi < NCLOUD * PTS_PAD) {   // init pads; compact overwrites ranks < total only
        half8 zq = {0, 0, 0, 0, 0, 0, 0, 0};
        half8 zr = {0, 0, 0, (_Float16)4096, 0, 0, 0, 0};   // pad ref: s=8*4096=32768 > any real
        Qfrag[gi] = zq;
        Rfrag[gi] = zr;
        nqint[gi] = 0.f;
    }
    int cloud = blockIdx.x >> 8;
    int chunk = blockIdx.x & 255;
    int t = threadIdx.x;
    const float* src = cloud_src(pred, tgt, cloud) + chunk * 1024;
    float4 v = reinterpret_cast<const float4*>(src)[t];
    int cnt = (v.x > 0.5f) + (v.y > 0.5f) + (v.z > 0.5f) + (v.w > 0.5f);
    __shared__ int s[256];
    s[t] = cnt; __syncthreads();
    for (int o = 128; o > 0; o >>= 1) {
        if (t < o) s[t] += s[t + o];
        __syncthreads();
    }
    if (t == 0) counts[cloud * NCHUNK + chunk] = s[0];
}

// ---- Kernel 2: exclusive scan of chunk counts per cloud --------------------
__global__ void k_scan(const int* __restrict__ counts, int* __restrict__ offsets,
                       int* __restrict__ totals) {
    int cloud = blockIdx.x;
    int t = threadIdx.x;
    int c = counts[cloud * NCHUNK + t];
    __shared__ int s[256];
    s[t] = c; __syncthreads();
    for (int o = 1; o < 256; o <<= 1) {
        int v = (t >= o) ? s[t - o] : 0;
        __syncthreads();
        s[t] += v;
        __syncthreads();
    }
    offsets[cloud * NCHUNK + t] = s[t] - c;
    if (t == 255) totals[cloud] = s[255];
}

// ---- Kernel 3: ordered compaction -> Q/R fragments + nq --------------------
__global__ void k_compact(const float* __restrict__ pred, const float* __restrict__ tgt,
                          const int* __restrict__ offsets,
                          half8* __restrict__ Qfrag, half8* __restrict__ Rfrag,
                          float* __restrict__ nqint) {
    int cloud = blockIdx.x >> 8;
    int chunk = blockIdx.x & 255;
    int t = threadIdx.x;
    const float* src = cloud_src(pred, tgt, cloud) + chunk * 1024;
    float4 v = reinterpret_cast<const float4*>(src)[t];
    int f0 = v.x > 0.5f, f1 = v.y > 0.5f, f2 = v.z > 0.5f, f3 = v.w > 0.5f;
    int cnt = f0 + f1 + f2 + f3;
    __shared__ int s[256];
    s[t] = cnt; __syncthreads();
    for (int o = 1; o < 256; o <<= 1) {
        int x = (t >= o) ? s[t - o] : 0;
        __syncthreads();
        s[t] += x;
        __syncthreads();
    }
    int rank = offsets[cloud * NCHUNK + chunk] + (s[t] - cnt);
    int eidx = chunk * 1024 + t * 4;
    int flags[4] = {f0, f1, f2, f3};
    size_t base = (size_t)cloud * PTS_PAD;
    #pragma unroll
    for (int e = 0; e < 4; ++e) {
        if (flags[e]) {
            if (rank < MAXPTS) {
                int idx = eidx + e;
                int d = idx >> 12, h = (idx >> 6) & 63, w = idx & 63;
                int nr = d * d + h * h + w * w;
                half8 Q = {(_Float16)(-2 * d), (_Float16)(-2 * h), (_Float16)(-2 * w),
                           (_Float16)8, (_Float16)1, 0, 0, 0};
                half8 R = {(_Float16)d, (_Float16)h, (_Float16)w,
                           (_Float16)(nr >> 3), (_Float16)(nr & 7), 0, 0, 0};
                Qfrag[base + rank] = Q;
                Rfrag[base + rank] = R;
                nqint[base + rank] = (float)nr;
            }
            rank++;
        }
    }
}

// ---- min3-shaped reduce of one f32x16 + carry ------------------------------
__device__ __forceinline__ float red16(f32x16 d, float m) {
    float t0 = fminf(fminf(d[0], d[1]), d[2]);
    float t1 = fminf(fminf(d[3], d[4]), d[5]);
    float t2 = fminf(fminf(d[6], d[7]), d[8]);
    float t3 = fminf(fminf(d[9], d[10]), d[11]);
    float t4 = fminf(fminf(d[12], d[13]), d[14]);
    float t5 = fminf(d[15], m);
    float u0 = fminf(fminf(t0, t1), t2);
    float u1 = fminf(fminf(t3, t4), t5);
    return fminf(u0, u1);
}

// two MFMAs + hazard pad in ONE asm block; "=&v" forces VGPR-class dests
// disjoint from srcs. 4x s_nop 7 = 32 cyc covers MFMA->VALU dest-read wait
// states for ANY post-block read order. No sched_barrier: compiler schedules.
#define MM2(dd0, dd1, aa, bb0, bb1)                                            \
    asm("v_mfma_f32_32x32x16_f16 %0, %2, %3, 0\n\t"                            \
        "v_mfma_f32_32x32x16_f16 %1, %2, %4, 0\n\t"                            \
        "s_nop 7\n\ts_nop 7\n\ts_nop 7\n\ts_nop 7"                             \
        : "=&v"(dd0), "=&v"(dd1)                                               \
        : "v"(aa), "v"(bb0), "v"(bb1))

// ---- Kernel 4: chamfer min via asm 32x32x16 MFMA, refs from L2 -------------
// grid = NTASK*NQB*RSPLIT = 1280 blocks (5/CU), 256 thr (4 waves), no LDS.
// Wave holds 64 queries (2 B-frags); streams 32 refs/step, depth-2 prefetch.
// Per step: 1 global_load_dwordx4 + 2 MFMA(asm) + ~18 v_min3. ~64 VGPR live.
__global__ __launch_bounds__(256, 5) void k_chamfer(const half8* __restrict__ Qfrag,
                                                    const half8* __restrict__ Rfrag,
                                                    float* __restrict__ smin) {
    int task = blockIdx.x / (NQB * RSPLIT);
    int rem  = blockIdx.x % (NQB * RSPLIT);
    int qb   = rem / RSPLIT;
    int rs   = rem % RSPLIT;
    int b = task >> 1, dir = task & 1;
    int qc = 2 * b + dir;
    int rc = 2 * b + (dir ^ 1);
    int tid = threadIdx.x, wave = tid >> 6, lane = tid & 63;
    int l32 = lane & 31;

    int qbase = qb * QPB + wave * QPW;
    half8 zero8 = {0, 0, 0, 0, 0, 0, 0, 0};
    half8 bq0 = zero8, bq1 = zero8;
    if (lane < 32) {   // lanes>=32 supply k=8..15: zero nullifies A garbage there
        const half8* qp = Qfrag + (size_t)qc * PTS_PAD + qbase + l32;
        bq0 = qp[0]; bq1 = qp[32];
    }
    float m0 = 1e30f, m1 = 1e30f;

    const half8* rp0 = Rfrag + (size_t)rc * PTS_PAD + rs * RLEN + l32;
    half8 a  = rp0[0];
    half8 an = rp0[32];

    for (int t = 0; t < RSTEPS - 2; ++t) {
        half8 a2 = rp0[32 * t + 64];   // depth-2 prefetch (~2 steps > L2 latency)
        f32x16 d0, d1;
        MM2(d0, d1, a, bq0, bq1);
        m0 = red16(d0, m0);
        m1 = red16(d1, m1);
        a = an;
        an = a2;
    }
    {
        f32x16 d0, d1;
        MM2(d0, d1, a, bq0, bq1);
        m0 = red16(d0, m0);
        m1 = red16(d1, m1);
        MM2(d0, d1, an, bq0, bq1);
        m0 = red16(d0, m0);
        m1 = red16(d1, m1);
    }

    // lane L and L+32 hold complementary ref-rows of query col (lane&31)
    m0 = fminf(m0, __shfl_xor(m0, 32));
    m1 = fminf(m1, __shfl_xor(m1, 32));
    if (lane < 32) {
        float* outp = smin + ((size_t)task * RSPLIT + rs) * PTS_PAD + qbase + l32;
        outp[0]  = m0;
        outp[32] = m1;
    }
}

// ---- Kernel 5: min over splits, add nq, scale, clamp, masked block sum -----
__global__ void k_reduce(const float* __restrict__ nqint, const int* __restrict__ totals,
                         const float* __restrict__ smin, float* __restrict__ bsum) {
    int task = blockIdx.x / NRB;
    int rb   = blockIdx.x % NRB;
    int tid  = threadIdx.x;
    int qi   = rb * 256 + tid;
    int qc   = 2 * (task >> 1) + (task & 1);
    int countQ = min(totals[qc], MAXPTS);

    const float SC2 = SCALE * SCALE;
    float contrib = 0.f;
    if (qi < countQ) {
        const float* s = smin + (size_t)task * RSPLIT * PTS_PAD + qi;
        float mn = fminf(fminf(s[0 * PTS_PAD], s[1 * PTS_PAD]),
                         fminf(s[2 * PTS_PAD], s[3 * PTS_PAD]));
        float nq = nqint[(size_t)qc * PTS_PAD + qi];
        contrib = fmaxf((nq + mn) * SC2, 0.f);
    }
    __shared__ float sb[256];
    sb[tid] = contrib; __syncthreads();
    for (int o = 128; o > 0; o >>= 1) {
        if (tid < o) sb[tid] += sb[tid + o];
        __syncthreads();
    }
    if (tid == 0) bsum[task * NRB + rb] = sb[0];
}

// ---- Kernel 6: deterministic final combine (8 parallel fixed-order sums) ---
__global__ void k_final(const float* __restrict__ bsum, const int* __restrict__ totals,
                        float* __restrict__ out) {
    int t = threadIdx.x;   // 64 threads
    __shared__ float sh[NTASK];
    if (t < NTASK) {
        float s = 0.f;
        #pragma unroll
        for (int i = 0; i < NRB; ++i) s += bsum[t * NRB + i];
        sh[t] = s;
    }
    __syncthreads();
    if (t == 0) {
        float total = 0.f, nv = 0.f;
        for (int b = 0; b < 4; ++b) {
            int c1 = min(totals[2 * b], MAXPTS);
            int c2 = min(totals[2 * b + 1], MAXPTS);
            float cd = sh[2 * b] / fmaxf((float)c1, 1.f) + sh[2 * b + 1] / fmaxf((float)c2, 1.f);
            if (c1 > 0 && c2 > 0) { total += cd; nv += 1.f; }
        }
        out[0] = (nv > 0.f) ? total / nv : 0.f;
    }
}

extern "C" void kernel_launch(void* const* d_in, const int* in_sizes, int n_in,
                              void* d_out, int out_size, void* d_ws, size_t ws_size,
                              hipStream_t stream) {
    const float* pred = (const float*)d_in[0];
    const float* tgt  = (const float*)d_in[1];
    float* out = (float*)d_out;

    char* ws = (char*)d_ws;
    int*   totals  = (int*)(ws + WS_TOTALS);
    int*   counts  = (int*)(ws + WS_COUNTS);
    int*   offsets = (int*)(ws + WS_OFFSETS);
    half8* Qfrag   = (half8*)(ws + WS_QFRAG);
    half8* Rfrag   = (half8*)(ws + WS_RFRAG);
    float* nqint   = (float*)(ws + WS_NQ);
    float* smin    = (float*)(ws + WS_SMIN);
    float* bsum    = (float*)(ws + WS_BSUM);

    k_count  <<<NCLOUD * NCHUNK, 256, 0, stream>>>(pred, tgt, counts, Qfrag, Rfrag, nqint);
    k_scan   <<<NCLOUD,          256, 0, stream>>>(counts, offsets, totals);
    k_compact<<<NCLOUD * NCHUNK, 256, 0, stream>>>(pred, tgt, offsets, Qfrag, Rfrag, nqint);
    k_chamfer<<<NTASK * NQB * RSPLIT, 256, 0, stream>>>(Qfrag, Rfrag, smin);
    k_reduce <<<NTASK * NRB,     256, 0, stream>>>(nqint, totals, smin, bsum);
    k_final  <<<1, 64, 0, stream>>>(bsum, totals, out);
}

// Round 12
// 58.884 us; speedup vs baseline: 1.0099x; 1.0099x over previous
//
#include <hip/hip_runtime.h>
#include <hip/hip_bf16.h>

// ChamferDistanceLoss via EXACT expanding-shell nearest-neighbor search.
// Selected points (first 10000 actives by flat index) of the ref cloud are
// encoded as a 64^3 occupancy BITMAP (32 KB), staged in LDS. Each query does
// Chebyshev shells r=0,1,2,... probing the bitmap; stop when r^2 > best
// (exact for any input; bounded by r<=63). For this data (p=0.5 dense slab)
// ~all queries finish after shell 1 (27 probes).
// dist^2 is an exact small int; normalized dist = D * (2/63)^2.

#define NVOX      262144
#define NCHUNK    256
#define MAXPTS    10000
#define PTS_PAD   10240
#define NCLOUD    8
#define NTASK     8
#define NRB       40            // NN/search blocks per task (256 q each)
#define NBM_WORDS 8192          // 64^3 bits / 32
#define SCALE     (2.0f/63.0f)

// ---------------- workspace layout (bytes) ----------------
#define WS_TOTALS   0           // 8 ints
#define WS_COUNTS   1024        // 8*256 ints
#define WS_OFFSETS  16384       // 8*256 ints
#define WS_QLIST    32768       // 8*10240 ints  = 327680
#define WS_BITMAP   360448      // 8*8192 uints  = 262144
#define WS_BSUM     622592      // 8*40 floats

__device__ __forceinline__ const float* cloud_src(const float* pred, const float* tgt, int cloud) {
    const float* base = (cloud & 1) ? tgt : pred;
    return base + (size_t)(cloud >> 1) * NVOX;
}

// ---- Kernel 1: per-chunk active counts (+ bitmap zero, merged) -------------
__global__ void k_count(const float* __restrict__ pred, const float* __restrict__ tgt,
                        int* __restrict__ counts, unsigned* __restrict__ bitmap) {
    int gi = blockIdx.x * 256 + threadIdx.x;
    if (gi < NCLOUD * NBM_WORDS) bitmap[gi] = 0u;
    int cloud = blockIdx.x >> 8;
    int chunk = blockIdx.x & 255;
    int t = threadIdx.x;
    const float* src = cloud_src(pred, tgt, cloud) + chunk * 1024;
    float4 v = reinterpret_cast<const float4*>(src)[t];
    int cnt = (v.x > 0.5f) + (v.y > 0.5f) + (v.z > 0.5f) + (v.w > 0.5f);
    __shared__ int s[256];
    s[t] = cnt; __syncthreads();
    for (int o = 128; o > 0; o >>= 1) {
        if (t < o) s[t] += s[t + o];
        __syncthreads();
    }
    if (t == 0) counts[cloud * NCHUNK + chunk] = s[0];
}

// ---- Kernel 2: exclusive scan of chunk counts per cloud --------------------
__global__ void k_scan(const int* __restrict__ counts, int* __restrict__ offsets,
                       int* __restrict__ totals) {
    int cloud = blockIdx.x;
    int t = threadIdx.x;
    int c = counts[cloud * NCHUNK + t];
    __shared__ int s[256];
    s[t] = c; __syncthreads();
    for (int o = 1; o < 256; o <<= 1) {
        int v = (t >= o) ? s[t - o] : 0;
        __syncthreads();
        s[t] += v;
        __syncthreads();
    }
    offsets[cloud * NCHUNK + t] = s[t] - c;
    if (t == 255) totals[cloud] = s[255];
}

// ---- Kernel 3: ordered compaction -> query index list + ref bitmap ---------
__global__ void k_compact(const float* __restrict__ pred, const float* __restrict__ tgt,
                          const int* __restrict__ offsets,
                          int* __restrict__ qlist, unsigned* __restrict__ bitmap) {
    int cloud = blockIdx.x >> 8;
    int chunk = blockIdx.x & 255;
    int t = threadIdx.x;
    const float* src = cloud_src(pred, tgt, cloud) + chunk * 1024;
    float4 v = reinterpret_cast<const float4*>(src)[t];
    int f0 = v.x > 0.5f, f1 = v.y > 0.5f, f2 = v.z > 0.5f, f3 = v.w > 0.5f;
    int cnt = f0 + f1 + f2 + f3;
    __shared__ int s[256];
    s[t] = cnt; __syncthreads();
    for (int o = 1; o < 256; o <<= 1) {
        int x = (t >= o) ? s[t - o] : 0;
        __syncthreads();
        s[t] += x;
        __syncthreads();
    }
    int rank = offsets[cloud * NCHUNK + chunk] + (s[t] - cnt);
    int eidx = chunk * 1024 + t * 4;
    int flags[4] = {f0, f1, f2, f3};
    #pragma unroll
    for (int e = 0; e < 4; ++e) {
        if (flags[e]) {
            if (rank < MAXPTS) {
                int idx = eidx + e;
                qlist[cloud * PTS_PAD + rank] = idx;
                atomicOr(&bitmap[cloud * NBM_WORDS + (idx >> 5)], 1u << (idx & 31));
            }
            rank++;
        }
    }
}

// ---- Kernel 4: exact NN via expanding Chebyshev shells over LDS bitmap -----
// grid = NTASK*NRB = 320 blocks, 256 thr, 1 query/thread.
// Stage ref bitmap (32 KB) -> LDS; shells r=0..63 with stop rule r^2 > best.
__global__ __launch_bounds__(256) void k_nn(const int* __restrict__ qlist,
                                            const unsigned* __restrict__ bitmap,
                                            const int* __restrict__ totals,
                                            float* __restrict__ bsum) {
    int task = blockIdx.x / NRB;
    int blk  = blockIdx.x % NRB;
    int b = task >> 1, dir = task & 1;
    int qc = 2 * b + dir;
    int rc = 2 * b + (dir ^ 1);
    int tid = threadIdx.x;

    __shared__ unsigned bm[NBM_WORDS];   // 32 KB
    {
        const uint4* src = (const uint4*)(bitmap + rc * NBM_WORDS);
        uint4* dst = (uint4*)bm;
        #pragma unroll
        for (int i = 0; i < 8; ++i) dst[tid + i * 256] = src[tid + i * 256];
    }
    __syncthreads();

    int countQ = min(totals[qc], MAXPTS);
    int countR = min(totals[rc], MAXPTS);
    int qi = blk * 256 + tid;

    float contrib = 0.f;
    if (qi < countQ && countR > 0) {
        int idx = qlist[qc * PTS_PAD + qi];
        int qd = idx >> 12, qh = (idx >> 6) & 63, qw = idx & 63;
        int best = 0x7fffffff;
        for (int r = 0; r <= 63; ++r) {
            if (r * r > best) break;
            for (int dz = -r; dz <= r; ++dz) {
                int z = qd + dz;
                if ((unsigned)z > 63u) continue;
                int zb = z << 12;
                int dz2 = dz * dz;
                for (int dy = -r; dy <= r; ++dy) {
                    int y = qh + dy;
                    if ((unsigned)y > 63u) continue;
                    int zyb = zb | (y << 6);
                    int dzy2 = dz2 + dy * dy;
                    bool face = (dz == -r) | (dz == r) | (dy == -r) | (dy == r);
                    if (face) {
                        for (int dx = -r; dx <= r; ++dx) {
                            int w = qw + dx;
                            if ((unsigned)w > 63u) continue;
                            int vid = zyb | w;
                            if ((bm[vid >> 5] >> (vid & 31)) & 1u)
                                best = min(best, dzy2 + dx * dx);
                        }
                    } else {
                        int w0 = qw - r, w1 = qw + r;
                        if ((unsigned)w0 <= 63u) {
                            int vid = zyb | w0;
                            if ((bm[vid >> 5] >> (vid & 31)) & 1u)
                                best = min(best, dzy2 + r * r);
                        }
                        if ((unsigned)w1 <= 63u) {
                            int vid = zyb | w1;
                            if ((bm[vid >> 5] >> (vid & 31)) & 1u)
                                best = min(best, dzy2 + r * r);
                        }
                    }
                }
            }
        }
        const float SC2 = SCALE * SCALE;
        contrib = (float)best * SC2;
    }

    __shared__ float sb[256];
    sb[tid] = contrib; __syncthreads();
    for (int o = 128; o > 0; o >>= 1) {
        if (tid < o) sb[tid] += sb[tid + o];
        __syncthreads();
    }
    if (tid == 0) bsum[task * NRB + blk] = sb[0];
}

// ---- Kernel 5: deterministic final combine (8 parallel fixed-order sums) ---
__global__ void k_final(const float* __restrict__ bsum, const int* __restrict__ totals,
                        float* __restrict__ out) {
    int t = threadIdx.x;   // 64 threads
    __shared__ float sh[NTASK];
    if (t < NTASK) {
        float s = 0.f;
        #pragma unroll
        for (int i = 0; i < NRB; ++i) s += bsum[t * NRB + i];
        sh[t] = s;
    }
    __syncthreads();
    if (t == 0) {
        float total = 0.f, nv = 0.f;
        for (int b = 0; b < 4; ++b) {
            int c1 = min(totals[2 * b], MAXPTS);
            int c2 = min(totals[2 * b + 1], MAXPTS);
            float cd = sh[2 * b] / fmaxf((float)c1, 1.f) + sh[2 * b + 1] / fmaxf((float)c2, 1.f);
            if (c1 > 0 && c2 > 0) { total += cd; nv += 1.f; }
        }
        out[0] = (nv > 0.f) ? total / nv : 0.f;
    }
}

extern "C" void kernel_launch(void* const* d_in, const int* in_sizes, int n_in,
                              void* d_out, int out_size, void* d_ws, size_t ws_size,
                              hipStream_t stream) {
    const float* pred = (const float*)d_in[0];
    const float* tgt  = (const float*)d_in[1];
    float* out = (float*)d_out;

    char* ws = (char*)d_ws;
    int*      totals  = (int*)(ws + WS_TOTALS);
    int*      counts  = (int*)(ws + WS_COUNTS);
    int*      offsets = (int*)(ws + WS_OFFSETS);
    int*      qlist   = (int*)(ws + WS_QLIST);
    unsigned* bitmap  = (unsigned*)(ws + WS_BITMAP);
    float*    bsum    = (float*)(ws + WS_BSUM);

    k_count  <<<NCLOUD * NCHUNK, 256, 0, stream>>>(pred, tgt, counts, bitmap);
    k_scan   <<<NCLOUD,          256, 0, stream>>>(counts, offsets, totals);
    k_compact<<<NCLOUD * NCHUNK, 256, 0, stream>>>(pred, tgt, offsets, qlist, bitmap);
    k_nn     <<<NTASK * NRB,     256, 0, stream>>>(qlist, bitmap, totals, bsum);
    k_final  <<<1, 64, 0, stream>>>(bsum, totals, out);
}

// Round 13
// 57.374 us; speedup vs baseline: 1.0365x; 1.0263x over previous
//
#include <hip/hip_runtime.h>
#include <hip/hip_bf16.h>

// ChamferDistanceLoss via EXACT fixed-window NN + rare shell fallback.
// Ref cloud's selected points (first 10000 actives) -> 64^3 bitmap (32 KB)
// staged in LDS. Each query probes its fully-unrolled 3x3x3 neighborhood
// (27 branch-free masked probes). If a hit exists, best<=3 < 4 <= any
// outside-window dist^2 -> exact. If no hit (P ~ 1e-8/query interior,
// ~2^-11 at slab corners), fall back to exact expanding Chebyshev shells
// r=2.. with stop rule r^2>best. dist^2 exact int; scale (2/63)^2 at end.

#define NVOX      262144
#define NCHUNK    256
#define MAXPTS    10000
#define PTS_PAD   10240
#define NCLOUD    8
#define NTASK     8
#define NRB       40            // NN blocks per task (256 q each)
#define NBM_WORDS 8192          // 64^3 bits / 32
#define SCALE     (2.0f/63.0f)

// ---------------- workspace layout (bytes) ----------------
#define WS_TOTALS   0           // 8 ints
#define WS_COUNTS   1024        // 8*256 ints
#define WS_QLIST    32768       // 8*10240 ints  = 327680
#define WS_BITMAP   360448      // 8*8192 uints  = 262144
#define WS_BSUM     622592      // 8*40 floats

__device__ __forceinline__ const float* cloud_src(const float* pred, const float* tgt, int cloud) {
    const float* base = (cloud & 1) ? tgt : pred;
    return base + (size_t)(cloud >> 1) * NVOX;
}

// ---- Kernel 1: per-chunk active counts (+ bitmap zero, merged) -------------
__global__ void k_count(const float* __restrict__ pred, const float* __restrict__ tgt,
                        int* __restrict__ counts, unsigned* __restrict__ bitmap) {
    int gi = blockIdx.x * 256 + threadIdx.x;
    if (gi < NCLOUD * NBM_WORDS) bitmap[gi] = 0u;
    int cloud = blockIdx.x >> 8;
    int chunk = blockIdx.x & 255;
    int t = threadIdx.x;
    const float* src = cloud_src(pred, tgt, cloud) + chunk * 1024;
    float4 v = reinterpret_cast<const float4*>(src)[t];
    int cnt = (v.x > 0.5f) + (v.y > 0.5f) + (v.z > 0.5f) + (v.w > 0.5f);
    __shared__ int s[256];
    s[t] = cnt; __syncthreads();
    for (int o = 128; o > 0; o >>= 1) {
        if (t < o) s[t] += s[t + o];
        __syncthreads();
    }
    if (t == 0) counts[cloud * NCHUNK + chunk] = s[0];
}

// ---- Kernel 2: compaction (scan folded in) -> qlist + ref bitmap -----------
__global__ void k_compact(const float* __restrict__ pred, const float* __restrict__ tgt,
                          const int* __restrict__ counts, int* __restrict__ totals,
                          int* __restrict__ qlist, unsigned* __restrict__ bitmap) {
    int cloud = blockIdx.x >> 8;
    int chunk = blockIdx.x & 255;
    int t = threadIdx.x;

    // in-block exclusive scan of this cloud's 256 chunk counts
    __shared__ int sc[256];
    sc[t] = counts[cloud * NCHUNK + t];
    __syncthreads();
    for (int o = 1; o < 256; o <<= 1) {
        int v = (t >= o) ? sc[t - o] : 0;
        __syncthreads();
        sc[t] += v;
        __syncthreads();
    }
    if (chunk == 0 && t == 255) totals[cloud] = sc[255];
    int chunk_base = sc[chunk] - counts[cloud * NCHUNK + chunk];   // exclusive
    __syncthreads();

    const float* src = cloud_src(pred, tgt, cloud) + chunk * 1024;
    float4 v = reinterpret_cast<const float4*>(src)[t];
    int f0 = v.x > 0.5f, f1 = v.y > 0.5f, f2 = v.z > 0.5f, f3 = v.w > 0.5f;
    int cnt = f0 + f1 + f2 + f3;
    __shared__ int s[256];
    s[t] = cnt; __syncthreads();
    for (int o = 1; o < 256; o <<= 1) {
        int x = (t >= o) ? s[t - o] : 0;
        __syncthreads();
        s[t] += x;
        __syncthreads();
    }
    int rank = chunk_base + (s[t] - cnt);
    int eidx = chunk * 1024 + t * 4;
    int flags[4] = {f0, f1, f2, f3};
    #pragma unroll
    for (int e = 0; e < 4; ++e) {
        if (flags[e]) {
            if (rank < MAXPTS) {
                int idx = eidx + e;
                qlist[cloud * PTS_PAD + rank] = idx;
                atomicOr(&bitmap[cloud * NBM_WORDS + (idx >> 5)], 1u << (idx & 31));
            }
            rank++;
        }
    }
}

// ---- Kernel 3: exact NN: branch-free 3x3x3 window + rare shell fallback ----
// grid = NTASK*NRB = 320 blocks, 256 thr, 1 query/thread.
__global__ __launch_bounds__(256) void k_nn(const int* __restrict__ qlist,
                                            const unsigned* __restrict__ bitmap,
                                            const int* __restrict__ totals,
                                            float* __restrict__ bsum) {
    int task = blockIdx.x / NRB;
    int blk  = blockIdx.x % NRB;
    int b = task >> 1, dir = task & 1;
    int qc = 2 * b + dir;
    int rc = 2 * b + (dir ^ 1);
    int tid = threadIdx.x;

    __shared__ unsigned bm[NBM_WORDS];   // 32 KB
    {
        const uint4* src = (const uint4*)(bitmap + rc * NBM_WORDS);
        uint4* dst = (uint4*)bm;
        #pragma unroll
        for (int i = 0; i < 8; ++i) dst[tid + i * 256] = src[tid + i * 256];
    }
    __syncthreads();

    int countQ = min(totals[qc], MAXPTS);
    int countR = min(totals[rc], MAXPTS);
    int qi = blk * 256 + tid;

    float contrib = 0.f;
    if (qi < countQ && countR > 0) {
        int idx = qlist[qc * PTS_PAD + qi];
        int qd = idx >> 12, qh = (idx >> 6) & 63, qw = idx & 63;
        int best = 0x7fffffff;

        // branch-free fully-unrolled 3x3x3 window (27 independent probes)
        #pragma unroll
        for (int dz = -1; dz <= 1; ++dz)
        #pragma unroll
        for (int dy = -1; dy <= 1; ++dy)
        #pragma unroll
        for (int dx = -1; dx <= 1; ++dx) {
            int z = qd + dz, y = qh + dy, w = qw + dx;
            bool ok = ((unsigned)z < 64u) & ((unsigned)y < 64u) & ((unsigned)w < 64u);
            int vid = ((z << 12) | (y << 6) | w) & (NVOX - 1);   // clamp for safety
            unsigned word = bm[vid >> 5];
            int d2 = dz * dz + dy * dy + dx * dx;                // compile-time
            if (ok && ((word >> (vid & 31)) & 1u)) best = min(best, d2);
        }

        // exact fallback (window hit => best<=3 < 4 <= outside => exact;
        // executed only on window miss, ~never)
        if (best == 0x7fffffff) {
            for (int r = 2; r <= 63; ++r) {
                if (r * r > best) break;
                for (int dz = -r; dz <= r; ++dz) {
                    int z = qd + dz;
                    if ((unsigned)z > 63u) continue;
                    int zb = z << 12;
                    int dz2 = dz * dz;
                    for (int dy = -r; dy <= r; ++dy) {
                        int y = qh + dy;
                        if ((unsigned)y > 63u) continue;
                        int zyb = zb | (y << 6);
                        int dzy2 = dz2 + dy * dy;
                        bool face = (dz == -r) | (dz == r) | (dy == -r) | (dy == r);
                        if (face) {
                            for (int dx = -r; dx <= r; ++dx) {
                                int w = qw + dx;
                                if ((unsigned)w > 63u) continue;
                                int vid = zyb | w;
                                if ((bm[vid >> 5] >> (vid & 31)) & 1u)
                                    best = min(best, dzy2 + dx * dx);
                            }
                        } else {
                            int w0 = qw - r, w1 = qw + r;
                            if ((unsigned)w0 <= 63u) {
                                int vid = zyb | w0;
                                if ((bm[vid >> 5] >> (vid & 31)) & 1u)
                                    best = min(best, dzy2 + r * r);
                            }
                            if ((unsigned)w1 <= 63u) {
                                int vid = zyb | w1;
                                if ((bm[vid >> 5] >> (vid & 31)) & 1u)
                                    best = min(best, dzy2 + r * r);
                            }
                        }
                    }
                }
            }
        }
        contrib = (float)best * (SCALE * SCALE);
    }

    __shared__ float sb[256];
    sb[tid] = contrib; __syncthreads();
    for (int o = 128; o > 0; o >>= 1) {
        if (tid < o) sb[tid] += sb[tid + o];
        __syncthreads();
    }
    if (tid == 0) bsum[task * NRB + blk] = sb[0];
}

// ---- Kernel 4: deterministic final combine (8 parallel fixed-order sums) ---
__global__ void k_final(const float* __restrict__ bsum, const int* __restrict__ totals,
                        float* __restrict__ out) {
    int t = threadIdx.x;   // 64 threads
    __shared__ float sh[NTASK];
    if (t < NTASK) {
        float s = 0.f;
        #pragma unroll
        for (int i = 0; i < NRB; ++i) s += bsum[t * NRB + i];
        sh[t] = s;
    }
    __syncthreads();
    if (t == 0) {
        float total = 0.f, nv = 0.f;
        for (int b = 0; b < 4; ++b) {
            int c1 = min(totals[2 * b], MAXPTS);
            int c2 = min(totals[2 * b + 1], MAXPTS);
            float cd = sh[2 * b] / fmaxf((float)c1, 1.f) + sh[2 * b + 1] / fmaxf((float)c2, 1.f);
            if (c1 > 0 && c2 > 0) { total += cd; nv += 1.f; }
        }
        out[0] = (nv > 0.f) ? total / nv : 0.f;
    }
}

extern "C" void kernel_launch(void* const* d_in, const int* in_sizes, int n_in,
                              void* d_out, int out_size, void* d_ws, size_t ws_size,
                              hipStream_t stream) {
    const float* pred = (const float*)d_in[0];
    const float* tgt  = (const float*)d_in[1];
    float* out = (float*)d_out;

    char* ws = (char*)d_ws;
    int*      totals  = (int*)(ws + WS_TOTALS);
    int*      counts  = (int*)(ws + WS_COUNTS);
    int*      qlist   = (int*)(ws + WS_QLIST);
    unsigned* bitmap  = (unsigned*)(ws + WS_BITMAP);
    float*    bsum    = (float*)(ws + WS_BSUM);

    k_count  <<<NCLOUD * NCHUNK, 256, 0, stream>>>(pred, tgt, counts, bitmap);
    k_compact<<<NCLOUD * NCHUNK, 256, 0, stream>>>(pred, tgt, counts, totals, qlist, bitmap);
    k_nn     <<<NTASK * NRB,     256, 0, stream>>>(qlist, bitmap, totals, bsum);
    k_final  <<<1, 64, 0, stream>>>(bsum, totals, out);
}